// Round 5
// baseline (152.742 us; speedup 1.0000x reference)
//
#include <hip/hip_runtime.h>

#define NROWS 8192
#define DDIM 256
#define MARGIN_F 0.2f
#define CSPLIT 32

typedef _Float16 half8 __attribute__((ext_vector_type(8)));
typedef float f32x4 __attribute__((ext_vector_type(4)));
typedef float f32x16 __attribute__((ext_vector_type(16)));
typedef int i32x4 __attribute__((ext_vector_type(4)));

__device__ __forceinline__ void gld16(const void* g, void* l) {
  __builtin_amdgcn_global_load_lds(
      (const __attribute__((address_space(1))) void*)g,
      (__attribute__((address_space(3))) void*)l, 16, 0, 0);
}

// ---------------- kernel 1: split fp32 -> hi/lo fp16, 32x32x16-MFMA-tiled + sq ----------------
// Chunk (rg=32-row group, kt=16-k tile) = 1024B at (rg*16+kt)*512 halves:
// [g 0..1][r 0..31][8 halves]; lane l of a wave maps to byte offset l*16 (r=l&31, g=l>>5).
__global__ __launch_bounds__(256)
void prep_kernel(const float* __restrict__ E, _Float16* __restrict__ Eh,
                 _Float16* __restrict__ El, float* __restrict__ sq) {
  __shared__ float scratch[256];
  const int t = threadIdx.x;
  const int r = t & 31;
  const int kseg = t >> 5;       // 0..7, covers k in [kseg*32, +32)
  const int rg = blockIdx.x;
  const int row = rg * 32 + r;
  const float* src = &E[row * DDIM + kseg * 32];
  float s = 0.f;
#pragma unroll
  for (int sub = 0; sub < 4; ++sub) {          // 8 k each
    const float4 f0 = *(const float4*)(src + sub * 8);
    const float4 f1 = *(const float4*)(src + sub * 8 + 4);
    const float v[8] = {f0.x, f0.y, f0.z, f0.w, f1.x, f1.y, f1.z, f1.w};
    half8 H, L;
#pragma unroll
    for (int e = 0; e < 8; ++e) {
      s = fmaf(v[e], v[e], s);
      const _Float16 hi = (_Float16)v[e];
      H[e] = hi;
      L[e] = (_Float16)(v[e] - (float)hi);
    }
    const int k0 = kseg * 32 + sub * 8;
    const int kt = k0 >> 4;
    const int g = (k0 >> 3) & 1;
    const int dst = (rg * 16 + kt) * 512 + g * 256 + r * 8;
    *(half8*)&Eh[dst] = H;
    *(half8*)&El[dst] = L;
  }
  scratch[t] = s;
  __syncthreads();
  if (t < 32) {
    float acc = 0.f;
#pragma unroll
    for (int seg = 0; seg < 8; ++seg) acc += scratch[seg * 32 + t];
    sq[rg * 32 + t] = acc;
  }
}

// ---------------- kernel 2: split-fp16 32x32x16 MFMA dist-GEMM + mining, 256x256 ----------------
// 512 thr = 8 waves: wi = w>>1 (0..3, 64-row i-quadrant = 2 frags), wj = w&1 (128-col j-half = 4 frags).
// D[j][i] via mfma(A=Ej, B=Ei): i = lane&31 (lane-local anchor),
// j = (reg&3) + 8*(reg>>2) + 4*(lane>>5).
// LDS: S[2 dbuf][4 arrays: SiH,SiL,SjH,SjL][8192 halves] = 128 KB.
__global__ __launch_bounds__(512, 2)
void mine_kernel(const _Float16* __restrict__ Eh, const _Float16* __restrict__ El,
                 const int* __restrict__ T, const float* __restrict__ sq,
                 float* __restrict__ pv, int* __restrict__ pi,
                 float* __restrict__ nv, int* __restrict__ ni) {
  __shared__ __align__(16) _Float16 S[2][4][8192];

  const int tid = threadIdx.x;
  const int lane = tid & 63;
  const int w = tid >> 6;
  const int wi = w >> 1, wj = w & 1;
  const int l31 = lane & 31;
  const int rowbase = blockIdx.y * 256;
  const int colbase = blockIdx.x * 256;

  // staging role: wave w stages array arr = w>>1, row-group half shalf = w&1 (8 chunks/kt)
  const int arr = w >> 1;
  const int shalf = w & 1;
  const _Float16* sA = (arr & 1) ? El : Eh;
  const int rgb = ((arr < 2) ? blockIdx.y : blockIdx.x) * 8;

  float sqi[2]; int ti[2];
#pragma unroll
  for (int fi = 0; fi < 2; ++fi) {
    const int i = rowbase + wi * 64 + fi * 32 + l31;
    sqi[fi] = sq[i];
    ti[fi] = T[i];
  }

  float bpv[2], bnv[2]; int bpi[2], bni[2];
#pragma unroll
  for (int fi = 0; fi < 2; ++fi) { bpv[fi] = -3e38f; bnv[fi] = 3e38f; bpi[fi] = 0; bni[fi] = 0; }

  f32x16 acc[4][2];
#pragma unroll
  for (int jf = 0; jf < 4; ++jf)
#pragma unroll
    for (int fi = 0; fi < 2; ++fi) acc[jf][fi] = (f32x16)(0.f);

  // prologue: stage ktg=0 (k-chunks 0,1) into buffer 0
#pragma unroll
  for (int c = 0; c < 8; ++c)
    gld16(sA + ((rgb + shalf * 4 + (c >> 1)) * 16 + (c & 1)) * 512 + lane * 8,
          &S[0][arr][((shalf * 4 + (c >> 1)) * 2 + (c & 1)) * 512]);
  __syncthreads();

  for (int ktg = 0; ktg < 8; ++ktg) {
    const int cur = ktg & 1;
#pragma unroll
    for (int p = 0; p < 2; ++p) {
      // issue 4 staging loads for ktg+1 into the other buffer
      if (ktg < 7) {
#pragma unroll
        for (int cc = 0; cc < 4; ++cc) {
          const int c = p * 4 + cc;
          gld16(sA + ((rgb + shalf * 4 + (c >> 1)) * 16 + (ktg + 1) * 2 + (c & 1)) * 512 + lane * 8,
                &S[cur ^ 1][arr][((shalf * 4 + (c >> 1)) * 2 + (c & 1)) * 512]);
        }
      }
      // fragment reads for this phase (ksub = p)
      half8 ajh[4], ajl[4];
#pragma unroll
      for (int jf = 0; jf < 4; ++jf) {
        const int o = ((wj * 4 + jf) * 2 + p) * 512 + lane * 8;
        ajh[jf] = *(const half8*)&S[cur][2][o];
        ajl[jf] = *(const half8*)&S[cur][3][o];
      }
      half8 bh[2], bl[2];
#pragma unroll
      for (int fi = 0; fi < 2; ++fi) {
        const int o = ((wi * 2 + fi) * 2 + p) * 512 + lane * 8;
        bh[fi] = *(const half8*)&S[cur][0][o];
        bl[fi] = *(const half8*)&S[cur][1][o];
      }
      __builtin_amdgcn_s_barrier();
      __builtin_amdgcn_s_setprio(1);
#pragma unroll
      for (int fi = 0; fi < 2; ++fi)
#pragma unroll
        for (int jf = 0; jf < 4; ++jf) {
          acc[jf][fi] = __builtin_amdgcn_mfma_f32_32x32x16_f16(ajh[jf], bh[fi], acc[jf][fi], 0, 0, 0);
          acc[jf][fi] = __builtin_amdgcn_mfma_f32_32x32x16_f16(ajl[jf], bh[fi], acc[jf][fi], 0, 0, 0);
          acc[jf][fi] = __builtin_amdgcn_mfma_f32_32x32x16_f16(ajh[jf], bl[fi], acc[jf][fi], 0, 0, 0);
        }
      __builtin_amdgcn_s_setprio(0);
      __builtin_amdgcn_s_barrier();
    }
    __syncthreads();   // drains own vmcnt (staging issued early -> ~free) + buffer swap safety
  }

  // epilogue: dist = sqi + sqj - 2*dot; online argmax(pos)/argmin(neg), first-index ties.
  // j = jfbase + 8*q + 4*(lane>>5) + (reg&3), ascending in (jf, q, reg&3) per lane.
  const int lh4 = (lane >> 5) * 4;
#pragma unroll
  for (int jf = 0; jf < 4; ++jf) {
    const int jfbase = colbase + wj * 128 + jf * 32;
#pragma unroll
    for (int q = 0; q < 4; ++q) {
      const int jb = jfbase + 8 * q + lh4;
      const f32x4 sqj = *(const f32x4*)&sq[jb];
      const i32x4 tj = *(const i32x4*)&T[jb];
#pragma unroll
      for (int fi = 0; fi < 2; ++fi) {
#pragma unroll
        for (int rr = 0; rr < 4; ++rr) {
          const float dst = fmaf(-2.f, acc[jf][fi][q * 4 + rr], sqi[fi] + sqj[rr]);
          const int jidx = jb + rr;
          if (ti[fi] == tj[rr]) {
            if (dst > bpv[fi]) { bpv[fi] = dst; bpi[fi] = jidx; }
          } else {
            if (dst < bnv[fi]) { bnv[fi] = dst; bni[fi] = jidx; }
          }
        }
      }
    }
  }

  // reduce across the two lane-halves (same anchor i, different j sets)
#pragma unroll
  for (int fi = 0; fi < 2; ++fi) {
    const float ov = __shfl_xor(bpv[fi], 32, 64);
    const int oi = __shfl_xor(bpi[fi], 32, 64);
    if (ov > bpv[fi] || (ov == bpv[fi] && oi < bpi[fi])) { bpv[fi] = ov; bpi[fi] = oi; }
    const float on = __shfl_xor(bnv[fi], 32, 64);
    const int oni = __shfl_xor(bni[fi], 32, 64);
    if (on < bnv[fi] || (on == bnv[fi] && oni < bni[fi])) { bnv[fi] = on; bni[fi] = oni; }
  }

  // combine the two j-waves (same wi) via LDS, then write partials
  __syncthreads();
  float4* scr = (float4*)&S[0][0][0];   // 256 entries
  if (wj == 1 && lane < 32) {
#pragma unroll
    for (int fi = 0; fi < 2; ++fi)
      scr[wi * 64 + fi * 32 + l31] =
          make_float4(bpv[fi], __int_as_float(bpi[fi]), bnv[fi], __int_as_float(bni[fi]));
  }
  __syncthreads();
  if (wj == 0 && lane < 32) {
#pragma unroll
    for (int fi = 0; fi < 2; ++fi) {
      const float4 o = scr[wi * 64 + fi * 32 + l31];
      const int oi = __float_as_int(o.y), oni = __float_as_int(o.w);
      if (o.x > bpv[fi] || (o.x == bpv[fi] && oi < bpi[fi])) { bpv[fi] = o.x; bpi[fi] = oi; }
      if (o.z < bnv[fi] || (o.z == bnv[fi] && oni < bni[fi])) { bnv[fi] = o.z; bni[fi] = oni; }
      const int row = rowbase + wi * 64 + fi * 32 + l31;
      const int oidx = row * CSPLIT + blockIdx.x;
      pv[oidx] = bpv[fi]; pi[oidx] = bpi[fi]; nv[oidx] = bnv[fi]; ni[oidx] = bni[fi];
    }
  }
}

// ---------------- kernel 3: combine splits, exact ap/an, losses, triplets ----------------
__global__ __launch_bounds__(256)
void finish_kernel(const float* __restrict__ E,
                   const float* __restrict__ pv, const int* __restrict__ pi,
                   const float* __restrict__ nv, const int* __restrict__ ni,
                   float* __restrict__ out, float* __restrict__ bl) {
  const int w = threadIdx.x >> 6, lane = threadIdx.x & 63;
  const int row = blockIdx.x * 4 + w;
  float Pv = -3e38f, Nv = 3e38f; int Pi = 0, Ni = 0;
#pragma unroll
  for (int s = 0; s < CSPLIT; ++s) {
    const float p = pv[row * CSPLIT + s]; const int px = pi[row * CSPLIT + s];
    if (p > Pv || (p == Pv && px < Pi)) { Pv = p; Pi = px; }
    const float n = nv[row * CSPLIT + s]; const int nx = ni[row * CSPLIT + s];
    if (n < Nv || (n == Nv && nx < Ni)) { Nv = n; Ni = nx; }
  }
  const float4 a = *(const float4*)&E[row * DDIM + lane * 4];
  const float4 p4 = *(const float4*)&E[Pi * DDIM + lane * 4];
  const float4 n4 = *(const float4*)&E[Ni * DDIM + lane * 4];
  float ap = (a.x - p4.x) * (a.x - p4.x) + (a.y - p4.y) * (a.y - p4.y)
           + (a.z - p4.z) * (a.z - p4.z) + (a.w - p4.w) * (a.w - p4.w);
  float an = (a.x - n4.x) * (a.x - n4.x) + (a.y - n4.y) * (a.y - n4.y)
           + (a.z - n4.z) * (a.z - n4.z) + (a.w - n4.w) * (a.w - n4.w);
#pragma unroll
  for (int o = 32; o > 0; o >>= 1) {
    ap += __shfl_down(ap, o, 64);
    an += __shfl_down(an, o, 64);
  }
  __shared__ float ls[4];
  if (lane == 0) {
    out[1 + row * 3 + 0] = (float)row;
    out[1 + row * 3 + 1] = (float)Pi;
    out[1 + row * 3 + 2] = (float)Ni;
    ls[w] = fmaxf(ap - an + MARGIN_F, 0.f);
  }
  __syncthreads();
  if (threadIdx.x == 0) bl[blockIdx.x] = (ls[0] + ls[1]) + (ls[2] + ls[3]);
}

// ---------------- kernel 4: deterministic mean ----------------
__global__ __launch_bounds__(256)
void sum_kernel(const float* __restrict__ bl, float* __restrict__ out) {
  __shared__ float s[256];
  float t = 0.f;
#pragma unroll
  for (int r = 0; r < (NROWS / 4) / 256; ++r) t += bl[threadIdx.x + r * 256];
  s[threadIdx.x] = t;
  __syncthreads();
  for (int o = 128; o > 0; o >>= 1) {
    if (threadIdx.x < o) s[threadIdx.x] += s[threadIdx.x + o];
    __syncthreads();
  }
  if (threadIdx.x == 0) out[0] = s[0] * (1.f / NROWS);
}

extern "C" void kernel_launch(void* const* d_in, const int* in_sizes, int n_in,
                              void* d_out, int out_size, void* d_ws, size_t ws_size,
                              hipStream_t stream) {
  const float* E = (const float*)d_in[0];
  const int* T = (const int*)d_in[1];
  float* out = (float*)d_out;

  // workspace carve-up (~12.05 MB)
  _Float16* Eh = (_Float16*)d_ws;                     // 4 MB
  _Float16* El = Eh + NROWS * DDIM;                   // 4 MB
  float* sq = (float*)(El + NROWS * DDIM);            // NROWS
  float* pv = sq + NROWS;                             // NROWS*CSPLIT (1 MB)
  int*   pi = (int*)(pv + NROWS * CSPLIT);
  float* nv = (float*)(pi + NROWS * CSPLIT);
  int*   ni = (int*)(nv + NROWS * CSPLIT);
  float* bl = (float*)(ni + NROWS * CSPLIT);          // NROWS/4

  prep_kernel<<<NROWS / 32, 256, 0, stream>>>(E, Eh, El, sq);
  mine_kernel<<<dim3(NROWS / 256, NROWS / 256), 512, 0, stream>>>(Eh, El, T, sq, pv, pi, nv, ni);
  finish_kernel<<<NROWS / 4, 256, 0, stream>>>(E, pv, pi, nv, ni, out, bl);
  sum_kernel<<<1, 256, 0, stream>>>(bl, out);
}